// Round 9
// baseline (101.212 us; speedup 1.0000x reference)
//
#include <hip/hip_runtime.h>

constexpr int D = 128;
constexpr int CAP = 48;         // slots per node; max degree for this input ~40 (Poisson λ=16)
constexpr int DPAD = 16;        // deg counter stride (ints): one counter per 64B line
constexpr int OVFCAP = 65536;   // overflow safety list (empty in practice)

typedef __attribute__((ext_vector_type(8))) short short8;   // 8 bf16 (4 VGPR)
typedef __attribute__((ext_vector_type(4))) float f32x4;    // MFMA accumulator

__device__ __forceinline__ unsigned short f2bf(float f) {   // RNE f32->bf16
    unsigned u = __float_as_uint(f);
    u += 0x7fffu + ((u >> 16) & 1u);
    return (unsigned short)(u >> 16);
}

// ---------------- prep: zero degP/ovfCnt + pack W -> fragment-ordered bf16 ----------------
// Wf[((kc*8 + t)*64 + l)*8 + j] = bf16( W[ kc*32 + (l>>4)*4 + (j&3) + (j>>2)*16 ][ t*16 + (l&15) ] )
__global__ __launch_bounds__(256) void k_prep(const float* __restrict__ W,
                                              unsigned short* __restrict__ Wf,
                                              uint4* __restrict__ zbase, int zcnt4) {
    int tid = blockIdx.x * 256 + threadIdx.x;   // 64 blocks x 256 = 16384
    // grid-stride zero of degP + ovfCnt (replaces hipMemsetAsync dispatch)
    for (int i = tid; i < zcnt4; i += 16384) zbase[i] = make_uint4(0u, 0u, 0u, 0u);

    int j  = tid & 7;
    int l  = (tid >> 3) & 63;
    int g  = tid >> 9;          // 0..31 = kc*8 + t
    int kc = g >> 3, t = g & 7;
    int k  = kc * 32 + ((l >> 4) * 4) + (j & 3) + ((j >> 2) * 16);
    int c  = t * 16 + (l & 15);
    Wf[tid] = f2bf(W[k * D + c]);
}

// ---------------- hybrid: slot placement (+degree) || MFMA GEMM (no LDS) ----------------
// even b, b/2 < gemmBlocks -> GEMM 64-row tile b/2 : y16[g][:] = bf16(seq[g] @ W)
// otherwise                -> placement: 2 edges/thread, slots[c*CAP + degP[c*16]++] = r
__global__ __launch_bounds__(256) void k_place_gemm(
        const int* __restrict__ row, const int* __restrict__ col,
        int* __restrict__ degP, int* __restrict__ slots,
        int* __restrict__ ovfCnt, int2* __restrict__ ovf, int E,
        int gemmBlocks,
        const float* __restrict__ seq, const unsigned short* __restrict__ Wf,
        unsigned short* __restrict__ y16, int n) {
    int b = (int)blockIdx.x;
    int half = b >> 1;
    bool isGemm = ((b & 1) == 0) && (half < gemmBlocks);

    if (!isGemm) {
        int pIdx = (b < 2 * gemmBlocks) ? half : (b - gemmBlocks);
        int t = pIdx * 256 + threadIdx.x;
        int e = 2 * t;
        if (e + 1 < E) {
            // nontemporal: col/row are streamed once; keep L2 for degP/slots
            unsigned long long cc = __builtin_nontemporal_load((const unsigned long long*)(col + e));
            unsigned long long rr = __builtin_nontemporal_load((const unsigned long long*)(row + e));
            int c0 = (int)(cc & 0xffffffffu), c1 = (int)(cc >> 32);
            int r0 = (int)(rr & 0xffffffffu), r1 = (int)(rr >> 32);
            int p0 = atomicAdd(&degP[(size_t)c0 * DPAD], 1);   // independent chains
            int p1 = atomicAdd(&degP[(size_t)c1 * DPAD], 1);
            if (p0 < CAP) slots[(size_t)c0 * CAP + p0] = r0;
            else { int o = atomicAdd(ovfCnt, 1); if (o < OVFCAP) ovf[o] = make_int2(r0, c0); }
            if (p1 < CAP) slots[(size_t)c1 * CAP + p1] = r1;
            else { int o = atomicAdd(ovfCnt, 1); if (o < OVFCAP) ovf[o] = make_int2(r1, c1); }
        } else if (e < E) {
            int c = col[e];
            int r = row[e];
            int p = atomicAdd(&degP[(size_t)c * DPAD], 1);
            if (p < CAP) slots[(size_t)c * CAP + p] = r;
            else { int o = atomicAdd(ovfCnt, 1); if (o < OVFCAP) ovf[o] = make_int2(r, c); }
        }
        return;
    }

    // ---- GEMM path: 64-row tile, 4 waves x 16 rows, N=128 (8 n-tiles), K=128 (4 chunks) ----
    int w  = threadIdx.x >> 6;    // wave 0..3
    int l  = threadIdx.x & 63;
    int lr = l & 15;              // A-row / C-col within tile
    int lg = l >> 4;              // 0..3

    int row0 = half * 64;
    int m = row0 + w * 16 + lr;
    if (m >= n) m = n - 1;        // clamp (partial last tile; stores guarded below)
    const float* sp = seq + (size_t)m * D;

    f32x4 acc[8];
    #pragma unroll
    for (int t = 0; t < 8; ++t) acc[t] = (f32x4){0.f, 0.f, 0.f, 0.f};

    const short8* WfB = (const short8*)Wf;

    #pragma unroll
    for (int kc = 0; kc < 4; ++kc) {
        int kb = kc * 32 + lg * 4;
        float4 lo = *(const float4*)(sp + kb);        // k = kb..kb+3
        float4 hi = *(const float4*)(sp + kb + 16);   // k = kb+16..kb+19
        short8 a;
        a[0] = (short)f2bf(lo.x); a[1] = (short)f2bf(lo.y);
        a[2] = (short)f2bf(lo.z); a[3] = (short)f2bf(lo.w);
        a[4] = (short)f2bf(hi.x); a[5] = (short)f2bf(hi.y);
        a[6] = (short)f2bf(hi.z); a[7] = (short)f2bf(hi.w);
        #pragma unroll
        for (int t = 0; t < 8; ++t) {
            short8 bf = WfB[(kc * 8 + t) * 64 + l];   // coalesced 16B, L1/L2-hot
            acc[t] = __builtin_amdgcn_mfma_f32_16x16x32_bf16(a, bf, acc[t], 0, 0, 0);
        }
    }

    // C/D: col = lane&15 (= lr), row = (lane>>4)*4 + reg (= lg*4 + i)
    #pragma unroll
    for (int i = 0; i < 4; ++i) {
        int g = row0 + w * 16 + lg * 4 + i;
        if (g < n) {
            unsigned short* yp = y16 + (size_t)g * D + lr;
            #pragma unroll
            for (int t = 0; t < 8; ++t) yp[t * 16] = f2bf(acc[t][i]);
        }
    }
}

// ---------------- dinv[i] = rsqrt(deg[i]+1), compact (L2-hot for k_agg) ----------------
__global__ __launch_bounds__(256) void k_dinv(const int* __restrict__ degP,
                                              float* __restrict__ dinv, int n) {
    int i = blockIdx.x * 256 + threadIdx.x;
    if (i < n) dinv[i] = rsqrtf((float)(degP[(size_t)i * DPAD] + 1));
}

// ---------------- per-node gather-reduce + norm + bias + PReLU ----------------
// out[c] = prelu( dc * ( y[c]*dc + sum_e y[r_e]*dinv[r_e] ) + b )
__global__ __launch_bounds__(256) void k_agg(
        const int* __restrict__ slots, const int* __restrict__ degP,
        const float* __restrict__ dinv,
        const int* __restrict__ ovfCnt, const int2* __restrict__ ovf,
        const unsigned short* __restrict__ y16,
        const float* __restrict__ b, const float* __restrict__ pw,
        float* __restrict__ out, int n) {
    int wid = (blockIdx.x * 256 + threadIdx.x) >> 6;   // one wave per node
    if (wid >= n) return;
    int lane = threadIdx.x & 63;

    int cntf = degP[(size_t)wid * DPAD];
    int cnt = cntf < CAP ? cntf : CAP;
    float dc = dinv[wid];

    // self-loop term gets one dc here, the second dc at the end
    unsigned sv = *(const unsigned*)(y16 + (size_t)wid * D + 2 * lane);
    float ax0 = __uint_as_float(sv << 16) * dc;
    float ay0 = __uint_as_float(sv & 0xffff0000u) * dc;
    float ax1 = 0.f, ay1 = 0.f, ax2 = 0.f, ay2 = 0.f, ax3 = 0.f, ay3 = 0.f;
    float ax4 = 0.f, ay4 = 0.f, ax5 = 0.f, ay5 = 0.f, ax6 = 0.f, ay6 = 0.f;
    float ax7 = 0.f, ay7 = 0.f;

    int my = (lane < cnt) ? slots[(size_t)wid * CAP + lane] : 0;

    int k = 0;
    for (; k + 7 < cnt; k += 8) {   // 8 independent gather chains in flight
        int r0 = __shfl(my, k);
        int r1 = __shfl(my, k + 1);
        int r2 = __shfl(my, k + 2);
        int r3 = __shfl(my, k + 3);
        int r4 = __shfl(my, k + 4);
        int r5 = __shfl(my, k + 5);
        int r6 = __shfl(my, k + 6);
        int r7 = __shfl(my, k + 7);
        float d0 = dinv[r0]; float d1 = dinv[r1]; float d2 = dinv[r2]; float d3 = dinv[r3];
        float d4 = dinv[r4]; float d5 = dinv[r5]; float d6 = dinv[r6]; float d7 = dinv[r7];
        unsigned v0 = *(const unsigned*)(y16 + (size_t)r0 * D + 2 * lane);
        unsigned v1 = *(const unsigned*)(y16 + (size_t)r1 * D + 2 * lane);
        unsigned v2 = *(const unsigned*)(y16 + (size_t)r2 * D + 2 * lane);
        unsigned v3 = *(const unsigned*)(y16 + (size_t)r3 * D + 2 * lane);
        unsigned v4 = *(const unsigned*)(y16 + (size_t)r4 * D + 2 * lane);
        unsigned v5 = *(const unsigned*)(y16 + (size_t)r5 * D + 2 * lane);
        unsigned v6 = *(const unsigned*)(y16 + (size_t)r6 * D + 2 * lane);
        unsigned v7 = *(const unsigned*)(y16 + (size_t)r7 * D + 2 * lane);
        ax0 = fmaf(__uint_as_float(v0 << 16), d0, ax0); ay0 = fmaf(__uint_as_float(v0 & 0xffff0000u), d0, ay0);
        ax1 = fmaf(__uint_as_float(v1 << 16), d1, ax1); ay1 = fmaf(__uint_as_float(v1 & 0xffff0000u), d1, ay1);
        ax2 = fmaf(__uint_as_float(v2 << 16), d2, ax2); ay2 = fmaf(__uint_as_float(v2 & 0xffff0000u), d2, ay2);
        ax3 = fmaf(__uint_as_float(v3 << 16), d3, ax3); ay3 = fmaf(__uint_as_float(v3 & 0xffff0000u), d3, ay3);
        ax4 = fmaf(__uint_as_float(v4 << 16), d4, ax4); ay4 = fmaf(__uint_as_float(v4 & 0xffff0000u), d4, ay4);
        ax5 = fmaf(__uint_as_float(v5 << 16), d5, ax5); ay5 = fmaf(__uint_as_float(v5 & 0xffff0000u), d5, ay5);
        ax6 = fmaf(__uint_as_float(v6 << 16), d6, ax6); ay6 = fmaf(__uint_as_float(v6 & 0xffff0000u), d6, ay6);
        ax7 = fmaf(__uint_as_float(v7 << 16), d7, ax7); ay7 = fmaf(__uint_as_float(v7 & 0xffff0000u), d7, ay7);
    }
    for (; k < cnt; ++k) {
        int r = __shfl(my, k);
        float dr = dinv[r];
        unsigned v = *(const unsigned*)(y16 + (size_t)r * D + 2 * lane);
        ax0 = fmaf(__uint_as_float(v << 16), dr, ax0);
        ay0 = fmaf(__uint_as_float(v & 0xffff0000u), dr, ay0);
    }

    if (cntf > CAP) {   // overflow drain (never taken for this input; correctness net)
        int m = *ovfCnt; if (m > OVFCAP) m = OVFCAP;
        for (int j = 0; j < m; ++j) {
            int2 pr = ovf[j];
            if (pr.y == wid) {
                float dr = dinv[pr.x];
                unsigned v = *(const unsigned*)(y16 + (size_t)pr.x * D + 2 * lane);
                ax0 = fmaf(__uint_as_float(v << 16), dr, ax0);
                ay0 = fmaf(__uint_as_float(v & 0xffff0000u), dr, ay0);
            }
        }
    }

    float sx = ((ax0 + ax1) + (ax2 + ax3)) + ((ax4 + ax5) + (ax6 + ax7));
    float sy = ((ay0 + ay1) + (ay2 + ay3)) + ((ay4 + ay5) + (ay6 + ay7));

    float2 bb = *(const float2*)(b + 2 * lane);
    float p = pw[0];
    float vx = sx * dc + bb.x;
    float vy = sy * dc + bb.y;
    vx = vx > 0.f ? vx : p * vx;
    vy = vy > 0.f ? vy : p * vy;
    *(float2*)(out + (size_t)wid * D + 2 * lane) = make_float2(vx, vy);
}

extern "C" void kernel_launch(void* const* d_in, const int* in_sizes, int n_in,
                              void* d_out, int out_size, void* d_ws, size_t ws_size,
                              hipStream_t stream) {
    const float* seq = (const float*)d_in[0];
    const int*   ei  = (const int*)d_in[1];   // [2, E]: row = ei, col = ei + E
    const float* W   = (const float*)d_in[2];
    const float* b   = (const float*)d_in[3];
    const float* pw  = (const float*)d_in[4];
    int n = in_sizes[0] / D;
    int E = in_sizes[1] / 2;

    float* out = (float*)d_out;

    // workspace layout (256B-aligned chunks): ~26.5 MB
    auto align = [](size_t x) { return (x + 255) & ~(size_t)255; };
    char* p = (char*)d_ws;
    unsigned short* y16 = (unsigned short*)p; p += align((size_t)n * D * sizeof(unsigned short));
    int*  degP   = (int*)p;   size_t degBytes = align((size_t)n * DPAD * sizeof(int)); p += degBytes;
    int*  ovfCnt = (int*)p;   p += 256;
    int2* ovf    = (int2*)p;  p += align((size_t)OVFCAP * sizeof(int2));
    int*  slots  = (int*)p;   p += align((size_t)n * CAP * sizeof(int));
    unsigned short* Wf = (unsigned short*)p; p += align((size_t)D * D * sizeof(unsigned short));
    float* dinv  = (float*)p; p += align((size_t)n * sizeof(float));

    // prep also zeroes degP+ovfCnt (grid-stride) — replaces the memset dispatch
    int zcnt4 = (int)((degBytes + 256) / 16);
    k_prep<<<64, 256, 0, stream>>>(W, Wf, (uint4*)degP, zcnt4);

    int GB = (n + 63) / 64;         // 782 GEMM tiles (64 rows)
    int PB = (E + 511) / 512;       // 1563 placement blocks (2 edges/thread)
    k_place_gemm<<<GB + PB, 256, 0, stream>>>(
        ei, ei + E, degP, slots, ovfCnt, ovf, E, GB, seq, Wf, y16, n);

    k_dinv<<<(n + 255) / 256, 256, 0, stream>>>(degP, dinv, n);

    k_agg<<<(unsigned)(((long long)n * 64 + 255) / 256), 256, 0, stream>>>(
        slots, degP, dinv, ovfCnt, ovf, y16, b, pw, out, n);
}

// Round 10
// 98.149 us; speedup vs baseline: 1.0312x; 1.0312x over previous
//
#include <hip/hip_runtime.h>

constexpr int D = 128;
constexpr int CAP = 48;         // slots per node; max degree for this input ~40 (Poisson λ=16)
constexpr int DPAD = 16;        // deg counter stride (ints): one counter per 64B line
constexpr int OVFCAP = 65536;   // overflow safety list (empty in practice)

typedef __attribute__((ext_vector_type(8))) short short8;   // 8 bf16 (4 VGPR)
typedef __attribute__((ext_vector_type(4))) float f32x4;    // MFMA accumulator

__device__ __forceinline__ unsigned short f2bf(float f) {   // RNE f32->bf16
    unsigned u = __float_as_uint(f);
    u += 0x7fffu + ((u >> 16) & 1u);
    return (unsigned short)(u >> 16);
}

// ---------------- prep: zero degP/ovfCnt + pack W -> fragment-ordered bf16 ----------------
// Wf[((kc*8 + t)*64 + l)*8 + j] = bf16( W[ kc*32 + (l>>4)*4 + (j&3) + (j>>2)*16 ][ t*16 + (l&15) ] )
__global__ __launch_bounds__(256) void k_prep(const float* __restrict__ W,
                                              unsigned short* __restrict__ Wf,
                                              uint4* __restrict__ zbase, int zcnt4) {
    int tid = blockIdx.x * 256 + threadIdx.x;   // 64 blocks x 256 = 16384
    // grid-stride zero of degP + ovfCnt (replaces hipMemsetAsync dispatch)
    for (int i = tid; i < zcnt4; i += 16384) zbase[i] = make_uint4(0u, 0u, 0u, 0u);

    int j  = tid & 7;
    int l  = (tid >> 3) & 63;
    int g  = tid >> 9;          // 0..31 = kc*8 + t
    int kc = g >> 3, t = g & 7;
    int k  = kc * 32 + ((l >> 4) * 4) + (j & 3) + ((j >> 2) * 16);
    int c  = t * 16 + (l & 15);
    Wf[tid] = f2bf(W[k * D + c]);
}

// ---------------- hybrid: slot placement (+degree) || MFMA GEMM (no LDS) ----------------
// b < 2*placeBlocks: even b -> placement b/2, odd b -> GEMM b/2
// b >= 2*placeBlocks:          -> GEMM (b - placeBlocks)
// placement: 8 edges/thread, slots[c*CAP + degP[c*16]++] = r  (deep atomic MLP)
__global__ __launch_bounds__(256) void k_place_gemm(
        const int* __restrict__ row, const int* __restrict__ col,
        int* __restrict__ degP, int* __restrict__ slots,
        int* __restrict__ ovfCnt, int2* __restrict__ ovf, int E,
        int placeBlocks,
        const float* __restrict__ seq, const unsigned short* __restrict__ Wf,
        unsigned short* __restrict__ y16, int n) {
    int b = (int)blockIdx.x;
    bool isPlace;
    int pIdx = 0, gIdx = 0;
    if (b < 2 * placeBlocks) {
        if ((b & 1) == 0) { isPlace = true;  pIdx = b >> 1; }
        else              { isPlace = false; gIdx = b >> 1; }
    } else {
        isPlace = false; gIdx = b - placeBlocks;
    }

    if (isPlace) {
        int t = pIdx * 256 + threadIdx.x;
        int e = 8 * t;
        if (e + 7 < E) {
            int4 ca = *(const int4*)(col + e);
            int4 cb = *(const int4*)(col + e + 4);
            int4 ra = *(const int4*)(row + e);
            int4 rb = *(const int4*)(row + e + 4);
            // 8 independent atomic chains in flight (counters 64B apart)
            int p0 = atomicAdd(&degP[(size_t)ca.x * DPAD], 1);
            int p1 = atomicAdd(&degP[(size_t)ca.y * DPAD], 1);
            int p2 = atomicAdd(&degP[(size_t)ca.z * DPAD], 1);
            int p3 = atomicAdd(&degP[(size_t)ca.w * DPAD], 1);
            int p4 = atomicAdd(&degP[(size_t)cb.x * DPAD], 1);
            int p5 = atomicAdd(&degP[(size_t)cb.y * DPAD], 1);
            int p6 = atomicAdd(&degP[(size_t)cb.z * DPAD], 1);
            int p7 = atomicAdd(&degP[(size_t)cb.w * DPAD], 1);
            if (p0 < CAP) slots[(size_t)ca.x * CAP + p0] = ra.x;
            else { int o = atomicAdd(ovfCnt, 1); if (o < OVFCAP) ovf[o] = make_int2(ra.x, ca.x); }
            if (p1 < CAP) slots[(size_t)ca.y * CAP + p1] = ra.y;
            else { int o = atomicAdd(ovfCnt, 1); if (o < OVFCAP) ovf[o] = make_int2(ra.y, ca.y); }
            if (p2 < CAP) slots[(size_t)ca.z * CAP + p2] = ra.z;
            else { int o = atomicAdd(ovfCnt, 1); if (o < OVFCAP) ovf[o] = make_int2(ra.z, ca.z); }
            if (p3 < CAP) slots[(size_t)ca.w * CAP + p3] = ra.w;
            else { int o = atomicAdd(ovfCnt, 1); if (o < OVFCAP) ovf[o] = make_int2(ra.w, ca.w); }
            if (p4 < CAP) slots[(size_t)cb.x * CAP + p4] = rb.x;
            else { int o = atomicAdd(ovfCnt, 1); if (o < OVFCAP) ovf[o] = make_int2(rb.x, cb.x); }
            if (p5 < CAP) slots[(size_t)cb.y * CAP + p5] = rb.y;
            else { int o = atomicAdd(ovfCnt, 1); if (o < OVFCAP) ovf[o] = make_int2(rb.y, cb.y); }
            if (p6 < CAP) slots[(size_t)cb.z * CAP + p6] = rb.z;
            else { int o = atomicAdd(ovfCnt, 1); if (o < OVFCAP) ovf[o] = make_int2(rb.z, cb.z); }
            if (p7 < CAP) slots[(size_t)cb.w * CAP + p7] = rb.w;
            else { int o = atomicAdd(ovfCnt, 1); if (o < OVFCAP) ovf[o] = make_int2(rb.w, cb.w); }
        } else {
            for (int j = 0; j < 8; ++j) {
                int ej = e + j;
                if (ej < E) {
                    int c = col[ej];
                    int r = row[ej];
                    int p = atomicAdd(&degP[(size_t)c * DPAD], 1);
                    if (p < CAP) slots[(size_t)c * CAP + p] = r;
                    else { int o = atomicAdd(ovfCnt, 1); if (o < OVFCAP) ovf[o] = make_int2(r, c); }
                }
            }
        }
        return;
    }

    // ---- GEMM path: 64-row tile, 4 waves x 16 rows, N=128 (8 n-tiles), K=128 (4 chunks) ----
    int w  = threadIdx.x >> 6;    // wave 0..3
    int l  = threadIdx.x & 63;
    int lr = l & 15;              // A-row / C-col within tile
    int lg = l >> 4;              // 0..3

    int row0 = gIdx * 64;
    int m = row0 + w * 16 + lr;
    if (m >= n) m = n - 1;        // clamp (partial last tile; stores guarded below)
    const float* sp = seq + (size_t)m * D;

    f32x4 acc[8];
    #pragma unroll
    for (int t = 0; t < 8; ++t) acc[t] = (f32x4){0.f, 0.f, 0.f, 0.f};

    const short8* WfB = (const short8*)Wf;

    #pragma unroll
    for (int kc = 0; kc < 4; ++kc) {
        int kb = kc * 32 + lg * 4;
        float4 lo = *(const float4*)(sp + kb);        // k = kb..kb+3
        float4 hi = *(const float4*)(sp + kb + 16);   // k = kb+16..kb+19
        short8 a;
        a[0] = (short)f2bf(lo.x); a[1] = (short)f2bf(lo.y);
        a[2] = (short)f2bf(lo.z); a[3] = (short)f2bf(lo.w);
        a[4] = (short)f2bf(hi.x); a[5] = (short)f2bf(hi.y);
        a[6] = (short)f2bf(hi.z); a[7] = (short)f2bf(hi.w);
        #pragma unroll
        for (int t = 0; t < 8; ++t) {
            short8 bf = WfB[(kc * 8 + t) * 64 + l];   // coalesced 16B, L1/L2-hot
            acc[t] = __builtin_amdgcn_mfma_f32_16x16x32_bf16(a, bf, acc[t], 0, 0, 0);
        }
    }

    // C/D: col = lane&15 (= lr), row = (lane>>4)*4 + reg (= lg*4 + i)
    #pragma unroll
    for (int i = 0; i < 4; ++i) {
        int g = row0 + w * 16 + lg * 4 + i;
        if (g < n) {
            unsigned short* yp = y16 + (size_t)g * D + lr;
            #pragma unroll
            for (int t = 0; t < 8; ++t) yp[t * 16] = f2bf(acc[t][i]);
        }
    }
}

// ---------------- dinv[i] = rsqrt(deg[i]+1), compact (L2-hot for k_agg) ----------------
__global__ __launch_bounds__(256) void k_dinv(const int* __restrict__ degP,
                                              float* __restrict__ dinv, int n) {
    int i = blockIdx.x * 256 + threadIdx.x;
    if (i < n) dinv[i] = rsqrtf((float)(degP[(size_t)i * DPAD] + 1));
}

// ---------------- per-node gather-reduce + norm + bias + PReLU ----------------
// out[c] = prelu( dc * ( y[c]*dc + sum_e y[r_e]*dinv[r_e] ) + b )
__global__ __launch_bounds__(256) void k_agg(
        const int* __restrict__ slots, const int* __restrict__ degP,
        const float* __restrict__ dinv,
        const int* __restrict__ ovfCnt, const int2* __restrict__ ovf,
        const unsigned short* __restrict__ y16,
        const float* __restrict__ b, const float* __restrict__ pw,
        float* __restrict__ out, int n) {
    int wid = (blockIdx.x * 256 + threadIdx.x) >> 6;   // one wave per node
    if (wid >= n) return;
    int lane = threadIdx.x & 63;

    int cntf = degP[(size_t)wid * DPAD];
    int cnt = cntf < CAP ? cntf : CAP;
    float dc = dinv[wid];

    // self-loop term gets one dc here, the second dc at the end
    unsigned sv = *(const unsigned*)(y16 + (size_t)wid * D + 2 * lane);
    float ax0 = __uint_as_float(sv << 16) * dc;
    float ay0 = __uint_as_float(sv & 0xffff0000u) * dc;
    float ax1 = 0.f, ay1 = 0.f, ax2 = 0.f, ay2 = 0.f, ax3 = 0.f, ay3 = 0.f;
    float ax4 = 0.f, ay4 = 0.f, ax5 = 0.f, ay5 = 0.f, ax6 = 0.f, ay6 = 0.f;
    float ax7 = 0.f, ay7 = 0.f;

    int my = (lane < cnt) ? slots[(size_t)wid * CAP + lane] : 0;

    int k = 0;
    for (; k + 7 < cnt; k += 8) {   // 8 independent gather chains in flight
        int r0 = __shfl(my, k);
        int r1 = __shfl(my, k + 1);
        int r2 = __shfl(my, k + 2);
        int r3 = __shfl(my, k + 3);
        int r4 = __shfl(my, k + 4);
        int r5 = __shfl(my, k + 5);
        int r6 = __shfl(my, k + 6);
        int r7 = __shfl(my, k + 7);
        float d0 = dinv[r0]; float d1 = dinv[r1]; float d2 = dinv[r2]; float d3 = dinv[r3];
        float d4 = dinv[r4]; float d5 = dinv[r5]; float d6 = dinv[r6]; float d7 = dinv[r7];
        unsigned v0 = *(const unsigned*)(y16 + (size_t)r0 * D + 2 * lane);
        unsigned v1 = *(const unsigned*)(y16 + (size_t)r1 * D + 2 * lane);
        unsigned v2 = *(const unsigned*)(y16 + (size_t)r2 * D + 2 * lane);
        unsigned v3 = *(const unsigned*)(y16 + (size_t)r3 * D + 2 * lane);
        unsigned v4 = *(const unsigned*)(y16 + (size_t)r4 * D + 2 * lane);
        unsigned v5 = *(const unsigned*)(y16 + (size_t)r5 * D + 2 * lane);
        unsigned v6 = *(const unsigned*)(y16 + (size_t)r6 * D + 2 * lane);
        unsigned v7 = *(const unsigned*)(y16 + (size_t)r7 * D + 2 * lane);
        ax0 = fmaf(__uint_as_float(v0 << 16), d0, ax0); ay0 = fmaf(__uint_as_float(v0 & 0xffff0000u), d0, ay0);
        ax1 = fmaf(__uint_as_float(v1 << 16), d1, ax1); ay1 = fmaf(__uint_as_float(v1 & 0xffff0000u), d1, ay1);
        ax2 = fmaf(__uint_as_float(v2 << 16), d2, ax2); ay2 = fmaf(__uint_as_float(v2 & 0xffff0000u), d2, ay2);
        ax3 = fmaf(__uint_as_float(v3 << 16), d3, ax3); ay3 = fmaf(__uint_as_float(v3 & 0xffff0000u), d3, ay3);
        ax4 = fmaf(__uint_as_float(v4 << 16), d4, ax4); ay4 = fmaf(__uint_as_float(v4 & 0xffff0000u), d4, ay4);
        ax5 = fmaf(__uint_as_float(v5 << 16), d5, ax5); ay5 = fmaf(__uint_as_float(v5 & 0xffff0000u), d5, ay5);
        ax6 = fmaf(__uint_as_float(v6 << 16), d6, ax6); ay6 = fmaf(__uint_as_float(v6 & 0xffff0000u), d6, ay6);
        ax7 = fmaf(__uint_as_float(v7 << 16), d7, ax7); ay7 = fmaf(__uint_as_float(v7 & 0xffff0000u), d7, ay7);
    }
    for (; k < cnt; ++k) {
        int r = __shfl(my, k);
        float dr = dinv[r];
        unsigned v = *(const unsigned*)(y16 + (size_t)r * D + 2 * lane);
        ax0 = fmaf(__uint_as_float(v << 16), dr, ax0);
        ay0 = fmaf(__uint_as_float(v & 0xffff0000u), dr, ay0);
    }

    if (cntf > CAP) {   // overflow drain (never taken for this input; correctness net)
        int m = *ovfCnt; if (m > OVFCAP) m = OVFCAP;
        for (int j = 0; j < m; ++j) {
            int2 pr = ovf[j];
            if (pr.y == wid) {
                float dr = dinv[pr.x];
                unsigned v = *(const unsigned*)(y16 + (size_t)pr.x * D + 2 * lane);
                ax0 = fmaf(__uint_as_float(v << 16), dr, ax0);
                ay0 = fmaf(__uint_as_float(v & 0xffff0000u), dr, ay0);
            }
        }
    }

    float sx = ((ax0 + ax1) + (ax2 + ax3)) + ((ax4 + ax5) + (ax6 + ax7));
    float sy = ((ay0 + ay1) + (ay2 + ay3)) + ((ay4 + ay5) + (ay6 + ay7));

    float2 bb = *(const float2*)(b + 2 * lane);
    float p = pw[0];
    float vx = sx * dc + bb.x;
    float vy = sy * dc + bb.y;
    vx = vx > 0.f ? vx : p * vx;
    vy = vy > 0.f ? vy : p * vy;
    *(float2*)(out + (size_t)wid * D + 2 * lane) = make_float2(vx, vy);
}

extern "C" void kernel_launch(void* const* d_in, const int* in_sizes, int n_in,
                              void* d_out, int out_size, void* d_ws, size_t ws_size,
                              hipStream_t stream) {
    const float* seq = (const float*)d_in[0];
    const int*   ei  = (const int*)d_in[1];   // [2, E]: row = ei, col = ei + E
    const float* W   = (const float*)d_in[2];
    const float* b   = (const float*)d_in[3];
    const float* pw  = (const float*)d_in[4];
    int n = in_sizes[0] / D;
    int E = in_sizes[1] / 2;

    float* out = (float*)d_out;

    // workspace layout (256B-aligned chunks): ~26.5 MB
    auto align = [](size_t x) { return (x + 255) & ~(size_t)255; };
    char* p = (char*)d_ws;
    unsigned short* y16 = (unsigned short*)p; p += align((size_t)n * D * sizeof(unsigned short));
    int*  degP   = (int*)p;   size_t degBytes = align((size_t)n * DPAD * sizeof(int)); p += degBytes;
    int*  ovfCnt = (int*)p;   p += 256;
    int2* ovf    = (int2*)p;  p += align((size_t)OVFCAP * sizeof(int2));
    int*  slots  = (int*)p;   p += align((size_t)n * CAP * sizeof(int));
    unsigned short* Wf = (unsigned short*)p; p += align((size_t)D * D * sizeof(unsigned short));
    float* dinv  = (float*)p; p += align((size_t)n * sizeof(float));

    // prep also zeroes degP+ovfCnt (grid-stride) — replaces the memset dispatch
    int zcnt4 = (int)((degBytes + 256) / 16);
    k_prep<<<64, 256, 0, stream>>>(W, Wf, (uint4*)degP, zcnt4);

    int GB = (n + 63) / 64;          // 782 GEMM tiles (64 rows)
    int PB = (E + 2047) / 2048;      // 391 placement blocks (8 edges/thread)
    k_place_gemm<<<GB + PB, 256, 0, stream>>>(
        ei, ei + E, degP, slots, ovfCnt, ovf, E, PB, seq, Wf, y16, n);

    k_dinv<<<(n + 255) / 256, 256, 0, stream>>>(degP, dinv, n);

    k_agg<<<(unsigned)(((long long)n * 64 + 255) / 256), 256, 0, stream>>>(
        slots, degP, dinv, ovfCnt, ovf, y16, b, pw, out, n);
}

// Round 11
// 94.841 us; speedup vs baseline: 1.0672x; 1.0349x over previous
//
#include <hip/hip_runtime.h>

constexpr int D = 128;
constexpr int CAP = 48;         // slots per node; max degree for this input ~40 (Poisson λ=16)
constexpr int DPAD = 16;        // deg counter stride (ints): one counter per 64B line
constexpr int OVFCAP = 65536;   // overflow safety list (empty in practice)

typedef __attribute__((ext_vector_type(8))) short short8;   // 8 bf16 (4 VGPR)
typedef __attribute__((ext_vector_type(4))) float f32x4;    // MFMA accumulator

__device__ __forceinline__ unsigned short f2bf(float f) {   // RNE f32->bf16
    unsigned u = __float_as_uint(f);
    u += 0x7fffu + ((u >> 16) & 1u);
    return (unsigned short)(u >> 16);
}

// ---------------- prep: zero degP/ovfCnt + pack W -> fragment-ordered bf16 ----------------
// Wf[((kc*8 + t)*64 + l)*8 + j] = bf16( W[ kc*32 + (l>>4)*4 + (j&3) + (j>>2)*16 ][ t*16 + (l&15) ] )
__global__ __launch_bounds__(256) void k_prep(const float* __restrict__ W,
                                              unsigned short* __restrict__ Wf,
                                              uint4* __restrict__ zbase, int zcnt4) {
    int tid = blockIdx.x * 256 + threadIdx.x;   // 64 blocks x 256 = 16384
    for (int i = tid; i < zcnt4; i += 16384) zbase[i] = make_uint4(0u, 0u, 0u, 0u);

    int j  = tid & 7;
    int l  = (tid >> 3) & 63;
    int g  = tid >> 9;          // 0..31 = kc*8 + t
    int kc = g >> 3, t = g & 7;
    int k  = kc * 32 + ((l >> 4) * 4) + (j & 3) + ((j >> 2) * 16);
    int c  = t * 16 + (l & 15);
    Wf[tid] = f2bf(W[k * D + c]);
}

// ---------------- hybrid: slot placement (+degree) || MFMA GEMM (no LDS) ----------------
// even b, b/2 < gemmBlocks -> GEMM 64-row tile b/2 ; otherwise placement (4 edges/thread)
__global__ __launch_bounds__(256) void k_place_gemm(
        const int* __restrict__ row, const int* __restrict__ col,
        int* __restrict__ degP, int* __restrict__ slots,
        int* __restrict__ ovfCnt, int2* __restrict__ ovf, int E,
        int gemmBlocks,
        const float* __restrict__ seq, const unsigned short* __restrict__ Wf,
        unsigned short* __restrict__ y16, int n) {
    int b = (int)blockIdx.x;
    int half = b >> 1;
    bool isGemm = ((b & 1) == 0) && (half < gemmBlocks);

    if (!isGemm) {
        int pIdx = (b < 2 * gemmBlocks) ? half : (b - gemmBlocks);
        int t = pIdx * 256 + threadIdx.x;
        int e = 4 * t;
        if (e + 3 < E) {
            int4 c4 = *(const int4*)(col + e);
            int4 r4 = *(const int4*)(row + e);
            int p0 = atomicAdd(&degP[(size_t)c4.x * DPAD], 1);  // 4 independent chains,
            int p1 = atomicAdd(&degP[(size_t)c4.y * DPAD], 1);  // counters 64B apart
            int p2 = atomicAdd(&degP[(size_t)c4.z * DPAD], 1);
            int p3 = atomicAdd(&degP[(size_t)c4.w * DPAD], 1);
            if (p0 < CAP) slots[(size_t)c4.x * CAP + p0] = r4.x;
            else { int o = atomicAdd(ovfCnt, 1); if (o < OVFCAP) ovf[o] = make_int2(r4.x, c4.x); }
            if (p1 < CAP) slots[(size_t)c4.y * CAP + p1] = r4.y;
            else { int o = atomicAdd(ovfCnt, 1); if (o < OVFCAP) ovf[o] = make_int2(r4.y, c4.y); }
            if (p2 < CAP) slots[(size_t)c4.z * CAP + p2] = r4.z;
            else { int o = atomicAdd(ovfCnt, 1); if (o < OVFCAP) ovf[o] = make_int2(r4.z, c4.z); }
            if (p3 < CAP) slots[(size_t)c4.w * CAP + p3] = r4.w;
            else { int o = atomicAdd(ovfCnt, 1); if (o < OVFCAP) ovf[o] = make_int2(r4.w, c4.w); }
        } else {
            for (int j = 0; j < 4; ++j) {
                int ej = e + j;
                if (ej < E) {
                    int c = col[ej];
                    int r = row[ej];
                    int p = atomicAdd(&degP[(size_t)c * DPAD], 1);
                    if (p < CAP) slots[(size_t)c * CAP + p] = r;
                    else { int o = atomicAdd(ovfCnt, 1); if (o < OVFCAP) ovf[o] = make_int2(r, c); }
                }
            }
        }
        return;
    }

    // ---- GEMM path: 64-row tile, 4 waves x 16 rows, N=128 (8 n-tiles), K=128 (4 chunks) ----
    int w  = threadIdx.x >> 6;    // wave 0..3
    int l  = threadIdx.x & 63;
    int lr = l & 15;              // A-row / C-col within tile
    int lg = l >> 4;              // 0..3

    int row0 = half * 64;
    int m = row0 + w * 16 + lr;
    if (m >= n) m = n - 1;        // clamp (partial last tile; stores guarded below)
    const float* sp = seq + (size_t)m * D;

    f32x4 acc[8];
    #pragma unroll
    for (int t = 0; t < 8; ++t) acc[t] = (f32x4){0.f, 0.f, 0.f, 0.f};

    const short8* WfB = (const short8*)Wf;

    #pragma unroll
    for (int kc = 0; kc < 4; ++kc) {
        int kb = kc * 32 + lg * 4;
        float4 lo = *(const float4*)(sp + kb);        // k = kb..kb+3
        float4 hi = *(const float4*)(sp + kb + 16);   // k = kb+16..kb+19
        short8 a;
        a[0] = (short)f2bf(lo.x); a[1] = (short)f2bf(lo.y);
        a[2] = (short)f2bf(lo.z); a[3] = (short)f2bf(lo.w);
        a[4] = (short)f2bf(hi.x); a[5] = (short)f2bf(hi.y);
        a[6] = (short)f2bf(hi.z); a[7] = (short)f2bf(hi.w);
        #pragma unroll
        for (int t = 0; t < 8; ++t) {
            short8 bf = WfB[(kc * 8 + t) * 64 + l];   // coalesced 16B, L1/L2-hot
            acc[t] = __builtin_amdgcn_mfma_f32_16x16x32_bf16(a, bf, acc[t], 0, 0, 0);
        }
    }

    // C/D: col = lane&15 (= lr), row = (lane>>4)*4 + reg (= lg*4 + i)
    #pragma unroll
    for (int i = 0; i < 4; ++i) {
        int g = row0 + w * 16 + lg * 4 + i;
        if (g < n) {
            unsigned short* yp = y16 + (size_t)g * D + lr;
            #pragma unroll
            for (int t = 0; t < 8; ++t) yp[t * 16] = f2bf(acc[t][i]);
        }
    }
}

// ---------------- per-node gather-reduce + norm + bias + PReLU ----------------
// out[c] = prelu( dc * ( y[c]*dc + sum_e y[r_e]*dr_e ) + b ),  d* = rsqrt(degP[*]+1)
__global__ __launch_bounds__(256) void k_agg(
        const int* __restrict__ slots, const int* __restrict__ degP,
        const int* __restrict__ ovfCnt, const int2* __restrict__ ovf,
        const unsigned short* __restrict__ y16,
        const float* __restrict__ b, const float* __restrict__ pw,
        float* __restrict__ out, int n) {
    int wid = (blockIdx.x * 256 + threadIdx.x) >> 6;   // one wave per node
    if (wid >= n) return;
    int lane = threadIdx.x & 63;

    int cntf = degP[(size_t)wid * DPAD];
    int cnt = cntf < CAP ? cntf : CAP;
    float dc = rsqrtf((float)(cntf + 1));

    // self-loop term gets one dc here, the second dc at the end
    unsigned sv = *(const unsigned*)(y16 + (size_t)wid * D + 2 * lane);
    float ax0 = __uint_as_float(sv << 16) * dc;
    float ay0 = __uint_as_float(sv & 0xffff0000u) * dc;
    float ax1 = 0.f, ay1 = 0.f, ax2 = 0.f, ay2 = 0.f, ax3 = 0.f, ay3 = 0.f;
    float ax4 = 0.f, ay4 = 0.f, ax5 = 0.f, ay5 = 0.f, ax6 = 0.f, ay6 = 0.f;
    float ax7 = 0.f, ay7 = 0.f;

    int my = (lane < cnt) ? slots[(size_t)wid * CAP + lane] : 0;

    int k = 0;
    for (; k + 7 < cnt; k += 8) {   // 8 independent gather chains in flight
        int r0 = __shfl(my, k);
        int r1 = __shfl(my, k + 1);
        int r2 = __shfl(my, k + 2);
        int r3 = __shfl(my, k + 3);
        int r4 = __shfl(my, k + 4);
        int r5 = __shfl(my, k + 5);
        int r6 = __shfl(my, k + 6);
        int r7 = __shfl(my, k + 7);
        int g0 = degP[(size_t)r0 * DPAD]; int g1 = degP[(size_t)r1 * DPAD];
        int g2 = degP[(size_t)r2 * DPAD]; int g3 = degP[(size_t)r3 * DPAD];
        int g4 = degP[(size_t)r4 * DPAD]; int g5 = degP[(size_t)r5 * DPAD];
        int g6 = degP[(size_t)r6 * DPAD]; int g7 = degP[(size_t)r7 * DPAD];
        unsigned v0 = *(const unsigned*)(y16 + (size_t)r0 * D + 2 * lane);
        unsigned v1 = *(const unsigned*)(y16 + (size_t)r1 * D + 2 * lane);
        unsigned v2 = *(const unsigned*)(y16 + (size_t)r2 * D + 2 * lane);
        unsigned v3 = *(const unsigned*)(y16 + (size_t)r3 * D + 2 * lane);
        unsigned v4 = *(const unsigned*)(y16 + (size_t)r4 * D + 2 * lane);
        unsigned v5 = *(const unsigned*)(y16 + (size_t)r5 * D + 2 * lane);
        unsigned v6 = *(const unsigned*)(y16 + (size_t)r6 * D + 2 * lane);
        unsigned v7 = *(const unsigned*)(y16 + (size_t)r7 * D + 2 * lane);
        float dr0 = rsqrtf((float)(g0 + 1));
        float dr1 = rsqrtf((float)(g1 + 1));
        float dr2 = rsqrtf((float)(g2 + 1));
        float dr3 = rsqrtf((float)(g3 + 1));
        float dr4 = rsqrtf((float)(g4 + 1));
        float dr5 = rsqrtf((float)(g5 + 1));
        float dr6 = rsqrtf((float)(g6 + 1));
        float dr7 = rsqrtf((float)(g7 + 1));
        ax0 = fmaf(__uint_as_float(v0 << 16), dr0, ax0); ay0 = fmaf(__uint_as_float(v0 & 0xffff0000u), dr0, ay0);
        ax1 = fmaf(__uint_as_float(v1 << 16), dr1, ax1); ay1 = fmaf(__uint_as_float(v1 & 0xffff0000u), dr1, ay1);
        ax2 = fmaf(__uint_as_float(v2 << 16), dr2, ax2); ay2 = fmaf(__uint_as_float(v2 & 0xffff0000u), dr2, ay2);
        ax3 = fmaf(__uint_as_float(v3 << 16), dr3, ax3); ay3 = fmaf(__uint_as_float(v3 & 0xffff0000u), dr3, ay3);
        ax4 = fmaf(__uint_as_float(v4 << 16), dr4, ax4); ay4 = fmaf(__uint_as_float(v4 & 0xffff0000u), dr4, ay4);
        ax5 = fmaf(__uint_as_float(v5 << 16), dr5, ax5); ay5 = fmaf(__uint_as_float(v5 & 0xffff0000u), dr5, ay5);
        ax6 = fmaf(__uint_as_float(v6 << 16), dr6, ax6); ay6 = fmaf(__uint_as_float(v6 & 0xffff0000u), dr6, ay6);
        ax7 = fmaf(__uint_as_float(v7 << 16), dr7, ax7); ay7 = fmaf(__uint_as_float(v7 & 0xffff0000u), dr7, ay7);
    }
    for (; k < cnt; ++k) {
        int r = __shfl(my, k);
        float dr = rsqrtf((float)(degP[(size_t)r * DPAD] + 1));
        unsigned v = *(const unsigned*)(y16 + (size_t)r * D + 2 * lane);
        ax0 = fmaf(__uint_as_float(v << 16), dr, ax0);
        ay0 = fmaf(__uint_as_float(v & 0xffff0000u), dr, ay0);
    }

    if (cntf > CAP) {   // overflow drain (never taken for this input; correctness net)
        int m = *ovfCnt; if (m > OVFCAP) m = OVFCAP;
        for (int j = 0; j < m; ++j) {
            int2 pr = ovf[j];
            if (pr.y == wid) {
                float dr = rsqrtf((float)(degP[(size_t)pr.x * DPAD] + 1));
                unsigned v = *(const unsigned*)(y16 + (size_t)pr.x * D + 2 * lane);
                ax0 = fmaf(__uint_as_float(v << 16), dr, ax0);
                ay0 = fmaf(__uint_as_float(v & 0xffff0000u), dr, ay0);
            }
        }
    }

    float sx = ((ax0 + ax1) + (ax2 + ax3)) + ((ax4 + ax5) + (ax6 + ax7));
    float sy = ((ay0 + ay1) + (ay2 + ay3)) + ((ay4 + ay5) + (ay6 + ay7));

    float2 bb = *(const float2*)(b + 2 * lane);
    float p = pw[0];
    float vx = sx * dc + bb.x;
    float vy = sy * dc + bb.y;
    vx = vx > 0.f ? vx : p * vx;
    vy = vy > 0.f ? vy : p * vy;
    *(float2*)(out + (size_t)wid * D + 2 * lane) = make_float2(vx, vy);
}

extern "C" void kernel_launch(void* const* d_in, const int* in_sizes, int n_in,
                              void* d_out, int out_size, void* d_ws, size_t ws_size,
                              hipStream_t stream) {
    const float* seq = (const float*)d_in[0];
    const int*   ei  = (const int*)d_in[1];   // [2, E]: row = ei, col = ei + E
    const float* W   = (const float*)d_in[2];
    const float* b   = (const float*)d_in[3];
    const float* pw  = (const float*)d_in[4];
    int n = in_sizes[0] / D;
    int E = in_sizes[1] / 2;

    float* out = (float*)d_out;

    // workspace layout (256B-aligned chunks): ~26.4 MB
    auto align = [](size_t x) { return (x + 255) & ~(size_t)255; };
    char* p = (char*)d_ws;
    unsigned short* y16 = (unsigned short*)p; p += align((size_t)n * D * sizeof(unsigned short));
    int*  degP   = (int*)p;   size_t degBytes = align((size_t)n * DPAD * sizeof(int)); p += degBytes;
    int*  ovfCnt = (int*)p;   p += 256;
    int2* ovf    = (int2*)p;  p += align((size_t)OVFCAP * sizeof(int2));
    int*  slots  = (int*)p;   p += align((size_t)n * CAP * sizeof(int));
    unsigned short* Wf = (unsigned short*)p; p += align((size_t)D * D * sizeof(unsigned short));

    // prep also zeroes degP+ovfCnt (grid-stride) — replaces the memset dispatch
    int zcnt4 = (int)((degBytes + 256) / 16);
    k_prep<<<64, 256, 0, stream>>>(W, Wf, (uint4*)degP, zcnt4);

    int GB = (n + 63) / 64;          // 782 GEMM tiles (64 rows)
    int PB = (E + 1023) / 1024;      // 782 placement blocks (4 edges/thread)
    k_place_gemm<<<GB + PB, 256, 0, stream>>>(
        ei, ei + E, degP, slots, ovfCnt, ovf, E, GB, seq, Wf, y16, n);

    k_agg<<<(unsigned)(((long long)n * 64 + 255) / 256), 256, 0, stream>>>(
        slots, degP, ovfCnt, ovf, y16, b, pw, out, n);
}

// Round 12
// 90.808 us; speedup vs baseline: 1.1146x; 1.0444x over previous
//
#include <hip/hip_runtime.h>

constexpr int D = 128;
constexpr int CAP = 48;         // slots per node; max degree for this input ~40 (Poisson λ=16)
constexpr int DPAD = 16;        // deg counter stride (ints): one counter per 64B line
constexpr int OVFCAP = 65536;   // overflow safety list (empty in practice)

typedef __attribute__((ext_vector_type(8))) short short8;   // 8 bf16 (4 VGPR)
typedef __attribute__((ext_vector_type(4))) float f32x4;    // MFMA accumulator

__device__ __forceinline__ unsigned short f2bf(float f) {   // RNE f32->bf16
    unsigned u = __float_as_uint(f);
    u += 0x7fffu + ((u >> 16) & 1u);
    return (unsigned short)(u >> 16);
}

// ---------------- prep: zero degP/ovfCnt + pack W -> fragment-ordered bf16 ----------------
// Wf[((kc*8 + t)*64 + l)*8 + j] = bf16( W[ kc*32 + (l>>4)*4 + (j&3) + (j>>2)*16 ][ t*16 + (l&15) ] )
__global__ __launch_bounds__(256) void k_prep(const float* __restrict__ W,
                                              unsigned short* __restrict__ Wf,
                                              uint4* __restrict__ zbase, int zcnt4) {
    int tid = blockIdx.x * 256 + threadIdx.x;   // 64 blocks x 256 = 16384
    for (int i = tid; i < zcnt4; i += 16384) zbase[i] = make_uint4(0u, 0u, 0u, 0u);

    int j  = tid & 7;
    int l  = (tid >> 3) & 63;
    int g  = tid >> 9;          // 0..31 = kc*8 + t
    int kc = g >> 3, t = g & 7;
    int k  = kc * 32 + ((l >> 4) * 4) + (j & 3) + ((j >> 2) * 16);
    int c  = t * 16 + (l & 15);
    Wf[tid] = f2bf(W[k * D + c]);
}

// ---------------- hybrid: slot placement (+degree) || MFMA GEMM (no LDS) ----------------
// even b, b/2 < gemmBlocks -> GEMM 64-row tile b/2 ; otherwise placement (4 edges/thread)
__global__ __launch_bounds__(256) void k_place_gemm(
        const int* __restrict__ row, const int* __restrict__ col,
        int* __restrict__ degP, int* __restrict__ slots,
        int* __restrict__ ovfCnt, int2* __restrict__ ovf, int E,
        int gemmBlocks,
        const float* __restrict__ seq, const unsigned short* __restrict__ Wf,
        unsigned short* __restrict__ y16, int n) {
    int b = (int)blockIdx.x;
    int half = b >> 1;
    bool isGemm = ((b & 1) == 0) && (half < gemmBlocks);

    if (!isGemm) {
        int pIdx = (b < 2 * gemmBlocks) ? half : (b - gemmBlocks);
        int t = pIdx * 256 + threadIdx.x;
        int e = 4 * t;
        if (e + 3 < E) {
            int4 c4 = *(const int4*)(col + e);
            int4 r4 = *(const int4*)(row + e);
            int p0 = atomicAdd(&degP[(size_t)c4.x * DPAD], 1);  // 4 independent chains,
            int p1 = atomicAdd(&degP[(size_t)c4.y * DPAD], 1);  // counters 64B apart
            int p2 = atomicAdd(&degP[(size_t)c4.z * DPAD], 1);
            int p3 = atomicAdd(&degP[(size_t)c4.w * DPAD], 1);
            if (p0 < CAP) slots[(size_t)c4.x * CAP + p0] = r4.x;
            else { int o = atomicAdd(ovfCnt, 1); if (o < OVFCAP) ovf[o] = make_int2(r4.x, c4.x); }
            if (p1 < CAP) slots[(size_t)c4.y * CAP + p1] = r4.y;
            else { int o = atomicAdd(ovfCnt, 1); if (o < OVFCAP) ovf[o] = make_int2(r4.y, c4.y); }
            if (p2 < CAP) slots[(size_t)c4.z * CAP + p2] = r4.z;
            else { int o = atomicAdd(ovfCnt, 1); if (o < OVFCAP) ovf[o] = make_int2(r4.z, c4.z); }
            if (p3 < CAP) slots[(size_t)c4.w * CAP + p3] = r4.w;
            else { int o = atomicAdd(ovfCnt, 1); if (o < OVFCAP) ovf[o] = make_int2(r4.w, c4.w); }
        } else {
            for (int j = 0; j < 4; ++j) {
                int ej = e + j;
                if (ej < E) {
                    int c = col[ej];
                    int r = row[ej];
                    int p = atomicAdd(&degP[(size_t)c * DPAD], 1);
                    if (p < CAP) slots[(size_t)c * CAP + p] = r;
                    else { int o = atomicAdd(ovfCnt, 1); if (o < OVFCAP) ovf[o] = make_int2(r, c); }
                }
            }
        }
        return;
    }

    // ---- GEMM path: 64-row tile, 4 waves x 16 rows, N=128 (8 n-tiles), K=128 (4 chunks) ----
    int w  = threadIdx.x >> 6;    // wave 0..3
    int l  = threadIdx.x & 63;
    int lr = l & 15;              // A-row / C-col within tile
    int lg = l >> 4;              // 0..3

    int row0 = half * 64;
    int m = row0 + w * 16 + lr;
    if (m >= n) m = n - 1;        // clamp (partial last tile; stores guarded below)
    const float* sp = seq + (size_t)m * D;

    f32x4 acc[8];
    #pragma unroll
    for (int t = 0; t < 8; ++t) acc[t] = (f32x4){0.f, 0.f, 0.f, 0.f};

    const short8* WfB = (const short8*)Wf;

    #pragma unroll
    for (int kc = 0; kc < 4; ++kc) {
        int kb = kc * 32 + lg * 4;
        float4 lo = *(const float4*)(sp + kb);        // k = kb..kb+3
        float4 hi = *(const float4*)(sp + kb + 16);   // k = kb+16..kb+19
        short8 a;
        a[0] = (short)f2bf(lo.x); a[1] = (short)f2bf(lo.y);
        a[2] = (short)f2bf(lo.z); a[3] = (short)f2bf(lo.w);
        a[4] = (short)f2bf(hi.x); a[5] = (short)f2bf(hi.y);
        a[6] = (short)f2bf(hi.z); a[7] = (short)f2bf(hi.w);
        #pragma unroll
        for (int t = 0; t < 8; ++t) {
            short8 bf = WfB[(kc * 8 + t) * 64 + l];   // coalesced 16B, L1/L2-hot
            acc[t] = __builtin_amdgcn_mfma_f32_16x16x32_bf16(a, bf, acc[t], 0, 0, 0);
        }
    }

    // C/D: col = lane&15 (= lr), row = (lane>>4)*4 + reg (= lg*4 + i)
    #pragma unroll
    for (int i = 0; i < 4; ++i) {
        int g = row0 + w * 16 + lg * 4 + i;
        if (g < n) {
            unsigned short* yp = y16 + (size_t)g * D + lr;
            #pragma unroll
            for (int t = 0; t < 8; ++t) yp[t * 16] = f2bf(acc[t][i]);
        }
    }
}

// ---------------- dinv[i] = rsqrt(deg[i]+1), compact 200KB (L2-resident for k_agg) ----------------
__global__ __launch_bounds__(256) void k_dinv(const int* __restrict__ degP,
                                              float* __restrict__ dinv, int n) {
    int i = blockIdx.x * 256 + threadIdx.x;
    if (i < n) dinv[i] = rsqrtf((float)(degP[(size_t)i * DPAD] + 1));
}

// ---------------- per-node gather-reduce + norm + bias + PReLU ----------------
// out[c] = prelu( dc * ( y[c]*dc + sum_e y[r_e]*dinv[r_e] ) + b )
__global__ __launch_bounds__(256) void k_agg(
        const int* __restrict__ slots, const int* __restrict__ degP,
        const float* __restrict__ dinv,
        const int* __restrict__ ovfCnt, const int2* __restrict__ ovf,
        const unsigned short* __restrict__ y16,
        const float* __restrict__ b, const float* __restrict__ pw,
        float* __restrict__ out, int n) {
    int wid = (blockIdx.x * 256 + threadIdx.x) >> 6;   // one wave per node
    if (wid >= n) return;
    int lane = threadIdx.x & 63;

    int cntf = degP[(size_t)wid * DPAD];
    int cnt = cntf < CAP ? cntf : CAP;
    float dc = dinv[wid];

    // self-loop term gets one dc here, the second dc at the end
    unsigned sv = *(const unsigned*)(y16 + (size_t)wid * D + 2 * lane);
    float ax0 = __uint_as_float(sv << 16) * dc;
    float ay0 = __uint_as_float(sv & 0xffff0000u) * dc;
    float ax1 = 0.f, ay1 = 0.f, ax2 = 0.f, ay2 = 0.f, ax3 = 0.f, ay3 = 0.f;
    float ax4 = 0.f, ay4 = 0.f, ax5 = 0.f, ay5 = 0.f, ax6 = 0.f, ay6 = 0.f;
    float ax7 = 0.f, ay7 = 0.f;

    int my = (lane < cnt) ? slots[(size_t)wid * CAP + lane] : 0;

    int k = 0;
    for (; k + 7 < cnt; k += 8) {   // 8 independent gather chains in flight
        int r0 = __shfl(my, k);
        int r1 = __shfl(my, k + 1);
        int r2 = __shfl(my, k + 2);
        int r3 = __shfl(my, k + 3);
        int r4 = __shfl(my, k + 4);
        int r5 = __shfl(my, k + 5);
        int r6 = __shfl(my, k + 6);
        int r7 = __shfl(my, k + 7);
        float d0 = dinv[r0]; float d1 = dinv[r1]; float d2 = dinv[r2]; float d3 = dinv[r3];
        float d4 = dinv[r4]; float d5 = dinv[r5]; float d6 = dinv[r6]; float d7 = dinv[r7];
        unsigned v0 = *(const unsigned*)(y16 + (size_t)r0 * D + 2 * lane);
        unsigned v1 = *(const unsigned*)(y16 + (size_t)r1 * D + 2 * lane);
        unsigned v2 = *(const unsigned*)(y16 + (size_t)r2 * D + 2 * lane);
        unsigned v3 = *(const unsigned*)(y16 + (size_t)r3 * D + 2 * lane);
        unsigned v4 = *(const unsigned*)(y16 + (size_t)r4 * D + 2 * lane);
        unsigned v5 = *(const unsigned*)(y16 + (size_t)r5 * D + 2 * lane);
        unsigned v6 = *(const unsigned*)(y16 + (size_t)r6 * D + 2 * lane);
        unsigned v7 = *(const unsigned*)(y16 + (size_t)r7 * D + 2 * lane);
        ax0 = fmaf(__uint_as_float(v0 << 16), d0, ax0); ay0 = fmaf(__uint_as_float(v0 & 0xffff0000u), d0, ay0);
        ax1 = fmaf(__uint_as_float(v1 << 16), d1, ax1); ay1 = fmaf(__uint_as_float(v1 & 0xffff0000u), d1, ay1);
        ax2 = fmaf(__uint_as_float(v2 << 16), d2, ax2); ay2 = fmaf(__uint_as_float(v2 & 0xffff0000u), d2, ay2);
        ax3 = fmaf(__uint_as_float(v3 << 16), d3, ax3); ay3 = fmaf(__uint_as_float(v3 & 0xffff0000u), d3, ay3);
        ax4 = fmaf(__uint_as_float(v4 << 16), d4, ax4); ay4 = fmaf(__uint_as_float(v4 & 0xffff0000u), d4, ay4);
        ax5 = fmaf(__uint_as_float(v5 << 16), d5, ax5); ay5 = fmaf(__uint_as_float(v5 & 0xffff0000u), d5, ay5);
        ax6 = fmaf(__uint_as_float(v6 << 16), d6, ax6); ay6 = fmaf(__uint_as_float(v6 & 0xffff0000u), d6, ay6);
        ax7 = fmaf(__uint_as_float(v7 << 16), d7, ax7); ay7 = fmaf(__uint_as_float(v7 & 0xffff0000u), d7, ay7);
    }
    for (; k < cnt; ++k) {
        int r = __shfl(my, k);
        float dr = dinv[r];
        unsigned v = *(const unsigned*)(y16 + (size_t)r * D + 2 * lane);
        ax0 = fmaf(__uint_as_float(v << 16), dr, ax0);
        ay0 = fmaf(__uint_as_float(v & 0xffff0000u), dr, ay0);
    }

    if (cntf > CAP) {   // overflow drain (never taken for this input; correctness net)
        int m = *ovfCnt; if (m > OVFCAP) m = OVFCAP;
        for (int j = 0; j < m; ++j) {
            int2 pr = ovf[j];
            if (pr.y == wid) {
                float dr = dinv[pr.x];
                unsigned v = *(const unsigned*)(y16 + (size_t)pr.x * D + 2 * lane);
                ax0 = fmaf(__uint_as_float(v << 16), dr, ax0);
                ay0 = fmaf(__uint_as_float(v & 0xffff0000u), dr, ay0);
            }
        }
    }

    float sx = ((ax0 + ax1) + (ax2 + ax3)) + ((ax4 + ax5) + (ax6 + ax7));
    float sy = ((ay0 + ay1) + (ay2 + ay3)) + ((ay4 + ay5) + (ay6 + ay7));

    float2 bb = *(const float2*)(b + 2 * lane);
    float p = pw[0];
    float vx = sx * dc + bb.x;
    float vy = sy * dc + bb.y;
    vx = vx > 0.f ? vx : p * vx;
    vy = vy > 0.f ? vy : p * vy;
    *(float2*)(out + (size_t)wid * D + 2 * lane) = make_float2(vx, vy);
}

extern "C" void kernel_launch(void* const* d_in, const int* in_sizes, int n_in,
                              void* d_out, int out_size, void* d_ws, size_t ws_size,
                              hipStream_t stream) {
    const float* seq = (const float*)d_in[0];
    const int*   ei  = (const int*)d_in[1];   // [2, E]: row = ei, col = ei + E
    const float* W   = (const float*)d_in[2];
    const float* b   = (const float*)d_in[3];
    const float* pw  = (const float*)d_in[4];
    int n = in_sizes[0] / D;
    int E = in_sizes[1] / 2;

    float* out = (float*)d_out;

    // workspace layout (256B-aligned chunks): ~26.6 MB
    auto align = [](size_t x) { return (x + 255) & ~(size_t)255; };
    char* p = (char*)d_ws;
    unsigned short* y16 = (unsigned short*)p; p += align((size_t)n * D * sizeof(unsigned short));
    int*  degP   = (int*)p;   size_t degBytes = align((size_t)n * DPAD * sizeof(int)); p += degBytes;
    int*  ovfCnt = (int*)p;   p += 256;
    int2* ovf    = (int2*)p;  p += align((size_t)OVFCAP * sizeof(int2));
    int*  slots  = (int*)p;   p += align((size_t)n * CAP * sizeof(int));
    unsigned short* Wf = (unsigned short*)p; p += align((size_t)D * D * sizeof(unsigned short));
    float* dinv  = (float*)p; p += align((size_t)n * sizeof(float));

    // prep also zeroes degP+ovfCnt (grid-stride) — replaces the memset dispatch
    int zcnt4 = (int)((degBytes + 256) / 16);
    k_prep<<<64, 256, 0, stream>>>(W, Wf, (uint4*)degP, zcnt4);

    int GB = (n + 63) / 64;          // 782 GEMM tiles (64 rows)
    int PB = (E + 1023) / 1024;      // 782 placement blocks (4 edges/thread)
    k_place_gemm<<<GB + PB, 256, 0, stream>>>(
        ei, ei + E, degP, slots, ovfCnt, ovf, E, GB, seq, Wf, y16, n);

    k_dinv<<<(n + 255) / 256, 256, 0, stream>>>(degP, dinv, n);

    k_agg<<<(unsigned)(((long long)n * 64 + 255) / 256), 256, 0, stream>>>(
        slots, degP, dinv, ovfCnt, ovf, y16, b, pw, out, n);
}